// Round 7
// baseline (326.817 us; speedup 1.0000x reference)
//
#include <hip/hip_runtime.h>

#define NN 40000
#define NE 640000
#define F 128
#define NC 16

typedef __attribute__((ext_vector_type(8))) short bf16x8;   // 8 bf16 (4 VGPRs)
typedef __attribute__((ext_vector_type(4))) float f32x4;    // MFMA acc

// ws layout (bytes); total 23502336 < proven 23632384
#define OFF_ROWPTR 0u          // (NN+1) ints
#define OFF_FILL   163968u     // NN ints
#define OFF_BSUM   327936u     // 64 ints
#define OFF_SORTED 328192u     // NE ints -> 2888192
#define OFF_STATS  2888192u    // 512 f32: sum, sumsq, bn_a, bn_b (2048 B — do not shrink!)
#define OFF_BIAS2  2890240u    // 256 f32: bias2a[128], biasExtra[128]
#define OFF_W1LB   2891264u    // 128x128 bf16  (w1lb | w1rb contiguous 64 KB)
#define OFF_W1RB   2924032u
#define OFF_W2LB   2956800u    // BN-scale-folded (w2lb | w2rb contiguous 64 KB)
#define OFF_W2RB   2989568u
#define OFF_RBH    3022336u    // NN*F bf16 (h1)
#define OFF_AGGM   13262336u   // NN*F bf16 -> 23502336

__device__ __forceinline__ unsigned short f2b(float f) {   // f32 -> bf16 RNE
    unsigned u = __builtin_bit_cast(unsigned, f);
    return (unsigned short)((u + 0x7fffu + ((u >> 16) & 1u)) >> 16);
}
__device__ __forceinline__ float b2f(unsigned short s) {
    return __builtin_bit_cast(float, (unsigned)s << 16);
}
__device__ __forceinline__ unsigned pk2(float lo, float hi) {
    return (unsigned)f2b(lo) | ((unsigned)f2b(hi) << 16);
}
__device__ __forceinline__ bf16x8 ld8f(const float* p) {    // 8 f32 -> bf16x8
    float4 lo = *(const float4*)p;
    float4 hi = *(const float4*)(p + 4);
    bf16x8 r;
    r[0] = (short)f2b(lo.x); r[1] = (short)f2b(lo.y);
    r[2] = (short)f2b(lo.z); r[3] = (short)f2b(lo.w);
    r[4] = (short)f2b(hi.x); r[5] = (short)f2b(hi.y);
    r[6] = (short)f2b(hi.z); r[7] = (short)f2b(hi.w);
    return r;
}

__global__ __launch_bounds__(256) void k_hist(const int* __restrict__ ei, int* __restrict__ cnt) {
    int e = blockIdx.x * 256 + threadIdx.x;
    if (e < NE) atomicAdd(&cnt[ei[NE + e]], 1);
}

__global__ __launch_bounds__(1024) void k_scan1(const int* __restrict__ cnt, int* __restrict__ rowptr,
                                                int* __restrict__ bsum) {
    __shared__ int wsum[16];
    int t = threadIdx.x, b = blockIdx.x;
    int idx = b * 1024 + t;
    int v = (idx < NN) ? cnt[idx] : 0;
    int lane = t & 63, w = t >> 6;
    int val = v;
    #pragma unroll
    for (int off = 1; off < 64; off <<= 1) { int u = __shfl_up(val, off); if (lane >= off) val += u; }
    if (lane == 63) wsum[w] = val;
    __syncthreads();
    if (w == 0) {
        int x = (lane < 16) ? wsum[lane] : 0;
        #pragma unroll
        for (int off = 1; off < 16; off <<= 1) { int u = __shfl_up(x, off); if (lane >= off) x += u; }
        if (lane < 16) wsum[lane] = x;
    }
    __syncthreads();
    int excl = val - v + (w > 0 ? wsum[w - 1] : 0);
    if (idx < NN) rowptr[idx] = excl;
    if (t == 1023) bsum[b] = wsum[15];
}

__global__ __launch_bounds__(64) void k_scan2(int* __restrict__ bsum, int* __restrict__ rowptr) {
    int lane = threadIdx.x;
    int v = (lane < 40) ? bsum[lane] : 0;
    int val = v;
    #pragma unroll
    for (int off = 1; off < 64; off <<= 1) { int u = __shfl_up(val, off); if (lane >= off) val += u; }
    if (lane < 40) bsum[lane] = val - v;
    if (lane == 0) rowptr[NN] = NE;
}

__global__ __launch_bounds__(1024) void k_scan3(int* __restrict__ rowptr, const int* __restrict__ bsum,
                                                int* __restrict__ fill) {
    int t = threadIdx.x, b = blockIdx.x;
    int idx = b * 1024 + t;
    if (idx < NN) {
        int r = rowptr[idx] + bsum[b];
        rowptr[idx] = r;
        fill[idx] = r;
    }
}

__global__ __launch_bounds__(256) void k_scatter(const int* __restrict__ ei, int* __restrict__ fill,
                                                 int* __restrict__ sorted) {
    int e = blockIdx.x * 256 + threadIdx.x;
    if (e < NE) {
        int src = ei[e], dst = ei[NE + e];
        int pos = atomicAdd(&fill[dst], 1);
        sorted[pos] = src;
    }
}

__global__ __launch_bounds__(256) void k_wprep1(const float* __restrict__ W1l, const float* __restrict__ W1r,
                                                unsigned short* __restrict__ w1lb, unsigned short* __restrict__ w1rb) {
    int i = blockIdx.x * 256 + threadIdx.x;     // < 32768
    if (i < 16384) w1lb[i] = f2b(W1l[i]);
    else           w1rb[i - 16384] = f2b(W1r[i - 16384]);
}

__global__ __launch_bounds__(128) void k_bnfinal(float* __restrict__ stats, const float* __restrict__ gamma,
                                                 const float* __restrict__ beta) {
    int t = threadIdx.x;
    float mu  = stats[t] * (1.f / NN);
    float var = stats[F + t] * (1.f / NN) - mu * mu;
    float a = gamma[t] * rsqrtf(var + 1e-5f);
    stats[256 + t] = a;
    stats[384 + t] = beta[t] - mu * a;
}

// Fold BN affine into conv2 weights + bias vectors.
__global__ __launch_bounds__(256) void k_wprep2(const float* __restrict__ W2l, const float* __restrict__ W2r,
                                                const float* __restrict__ b2l, const float* __restrict__ stats,
                                                unsigned short* __restrict__ w2lb, unsigned short* __restrict__ w2rb,
                                                float* __restrict__ bias2) {
    int t = threadIdx.x;
    int o = t & 127;
    const float* W = (t < 128) ? W2l : W2r;
    unsigned short* wb = (t < 128) ? w2lb : w2rb;
    float dot = 0.f;
    for (int k = 0; k < F; ++k) {
        float w = W[o * F + k];
        wb[o * F + k] = f2b(w * stats[256 + k]);
        dot = fmaf(stats[384 + k], w, dot);
    }
    if (t < 128) bias2[128 + o] = dot;
    else         bias2[o] = b2l[o] + dot;
}

// Gather (neighbor mean): one wave per node; quarter q handles edge e+q, lane li covers 8 features.
template<int BF>
__global__ __launch_bounds__(256) void k_agg(
    const float* __restrict__ featf, const unsigned short* __restrict__ featb,
    const int* __restrict__ rowptr, const int* __restrict__ sorted,
    unsigned short* __restrict__ aggm)
{
    int node = (blockIdx.x << 2) + (threadIdx.x >> 6);
    int lane = threadIdx.x & 63;
    int q = lane >> 4, li = lane & 15;
    int fo = li << 3;
    int e0 = rowptr[node], e1 = rowptr[node + 1];
    int deg = e1 - e0;
    float a0=0.f,a1=0.f,a2=0.f,a3=0.f,a4=0.f,a5=0.f,a6=0.f,a7=0.f;

#define ACC_EDGE(SRC) do { \
        if constexpr (BF) { \
            uint4 u = *(const uint4*)&featb[(size_t)(SRC) * F + fo]; \
            a0 += b2f((unsigned short)(u.x & 0xffff)); a1 += b2f((unsigned short)(u.x >> 16)); \
            a2 += b2f((unsigned short)(u.y & 0xffff)); a3 += b2f((unsigned short)(u.y >> 16)); \
            a4 += b2f((unsigned short)(u.z & 0xffff)); a5 += b2f((unsigned short)(u.z >> 16)); \
            a6 += b2f((unsigned short)(u.w & 0xffff)); a7 += b2f((unsigned short)(u.w >> 16)); \
        } else { \
            const float* rp_ = featf + (size_t)(SRC) * F + fo; \
            float4 lo = *(const float4*)rp_; \
            float4 hi = *(const float4*)(rp_ + 4); \
            a0 += lo.x; a1 += lo.y; a2 += lo.z; a3 += lo.w; \
            a4 += hi.x; a5 += hi.y; a6 += hi.z; a7 += hi.w; \
        } } while (0)

    int e = e0;
    for (; e + 8 <= e1; e += 8) {
        int s0 = sorted[e + q];
        int s1 = sorted[e + 4 + q];
        ACC_EDGE(s0); ACC_EDGE(s1);
    }
    for (; e + 4 <= e1; e += 4) {
        int s0 = sorted[e + q];
        ACC_EDGE(s0);
    }
    if (e < e1 && q < (e1 - e)) {
        int s0 = sorted[e + q];
        ACC_EDGE(s0);
    }
#undef ACC_EDGE

    #pragma unroll
    for (int m = 16; m <= 32; m <<= 1) {
        a0 += __shfl_xor(a0, m); a1 += __shfl_xor(a1, m);
        a2 += __shfl_xor(a2, m); a3 += __shfl_xor(a3, m);
        a4 += __shfl_xor(a4, m); a5 += __shfl_xor(a5, m);
        a6 += __shfl_xor(a6, m); a7 += __shfl_xor(a7, m);
    }

    if (q == 0) {
        float inv = 1.f / (float)(deg > 1 ? deg : 1);
        uint4 o;
        o.x = pk2(a0 * inv, a1 * inv);
        o.y = pk2(a2 * inv, a3 * inv);
        o.z = pk2(a4 * inv, a5 * inv);
        o.w = pk2(a6 * inv, a7 * inv);
        *(uint4*)&aggm[(size_t)node * F + fo] = o;
    }
}

// MFMA dual GEMM, 64 nodes/block (4 waves x 16 rows x all 128 outs).
// Weights (64 KB bf16, wl|wr contiguous) staged in LDS with involutive XOR swizzle
// (addr ^= ((row&7)<<4)) so ds_read_b128 of a 16-row column slice is ~2-way conflict max.
// A-frags loaded upfront from global into regs. Row L2-norm fully in-register (16-lane shfl).
template<int CONV2>
__global__ __launch_bounds__(256) void k_gemm(
    const unsigned short* __restrict__ aggm,
    const float* __restrict__ xf,              // conv1 self rows (f32)
    const unsigned short* __restrict__ xb,     // conv2 self rows (bf16 h1)
    const unsigned short* __restrict__ wb64,   // 64 KB: wl (32KB) | wr (32KB)
    const float* __restrict__ bias1,           // conv1: b1l
    const float* __restrict__ bias2,           // conv2: [bias2a | biasExtra]
    const int* __restrict__ rowptr,
    unsigned short* __restrict__ rbh, float* __restrict__ stats,
    const float* __restrict__ Wfc, const float* __restrict__ bfc,
    float* __restrict__ out)
{
    __shared__ __align__(16) char smem[65536];
    int t = threadIdx.x;
    int nb = blockIdx.x * 64;
    int w = t >> 6, lane = t & 63;
    int li = lane & 15, kg = lane >> 4;
    int rowA = nb + w * 16 + li;           // A row this lane feeds

    // ---- A-fragment loads (all issued upfront) ----
    bf16x8 aA[4], aS[4];
    #pragma unroll
    for (int kc = 0; kc < 4; ++kc)
        aA[kc] = *(const bf16x8*)(aggm + (size_t)rowA * F + kg * 8 + kc * 32);
    #pragma unroll
    for (int kc = 0; kc < 4; ++kc) {
        if constexpr (CONV2)
            aS[kc] = *(const bf16x8*)(xb + (size_t)rowA * F + kg * 8 + kc * 32);
        else
            aS[kc] = ld8f(xf + (size_t)rowA * F + kg * 8 + kc * 32);
    }

    // ---- stage 64 KB weights into LDS (linear global read, swizzled LDS write) ----
    #pragma unroll
    for (int it = 0; it < 16; ++it) {
        unsigned d = (unsigned)(it * 256 + t) * 16u;
        uint4 wv = *(const uint4*)((const char*)wb64 + d);
        unsigned s = d ^ (((d >> 8) & 7u) << 4);
        *(uint4*)(smem + s) = wv;
    }
    __syncthreads();

    // ---- MFMA: 8 col-tiles, K=128 over 2 paths ----
    f32x4 acc[8];
    #pragma unroll
    for (int j = 0; j < 8; ++j) acc[j] = (f32x4){0.f, 0.f, 0.f, 0.f};

    #pragma unroll
    for (int kc = 0; kc < 4; ++kc) {
        #pragma unroll
        for (int j = 0; j < 8; ++j) {
            unsigned om = (unsigned)(j * 16 + li) * 256u + (unsigned)(kg * 16 + kc * 64);
            om ^= ((unsigned)(li & 7) << 4);
            bf16x8 bL = *(const bf16x8*)(smem + om);
            acc[j] = __builtin_amdgcn_mfma_f32_16x16x32_bf16(aA[kc], bL, acc[j], 0, 0, 0);
        }
        #pragma unroll
        for (int j = 0; j < 8; ++j) {
            unsigned om = (unsigned)(j * 16 + li) * 256u + (unsigned)(kg * 16 + kc * 64);
            om ^= ((unsigned)(li & 7) << 4);
            bf16x8 bR = *(const bf16x8*)(smem + 32768 + om);
            acc[j] = __builtin_amdgcn_mfma_f32_16x16x32_bf16(aS[kc], bR, acc[j], 0, 0, 0);
        }
    }

    // C/D layout: lane (li,kg) holds C[row16 = kg*4+r][col = j*16+li]
    // ---- bias + row L2-norm, fully in-register ----
    float ss[4] = {0.f, 0.f, 0.f, 0.f};
    if constexpr (!CONV2) {
        float bl[8];
        #pragma unroll
        for (int j = 0; j < 8; ++j) bl[j] = bias1[j * 16 + li];
        #pragma unroll
        for (int j = 0; j < 8; ++j)
            #pragma unroll
            for (int r = 0; r < 4; ++r) {
                float c = acc[j][r] + bl[j];
                acc[j][r] = c;
                ss[r] = fmaf(c, c, ss[r]);
            }
    } else {
        float b2a[8], b2e[8];
        #pragma unroll
        for (int j = 0; j < 8; ++j) { b2a[j] = bias2[j * 16 + li]; b2e[j] = bias2[128 + j * 16 + li]; }
        int rp[5];
        #pragma unroll
        for (int r = 0; r < 5; ++r) rp[r] = rowptr[nb + w * 16 + kg * 4 + r];
        float flg[4];
        #pragma unroll
        for (int r = 0; r < 4; ++r) flg[r] = (rp[r + 1] > rp[r]) ? 1.f : 0.f;
        #pragma unroll
        for (int j = 0; j < 8; ++j)
            #pragma unroll
            for (int r = 0; r < 4; ++r) {
                float c = acc[j][r] + b2a[j] + flg[r] * b2e[j];
                acc[j][r] = c;
                ss[r] = fmaf(c, c, ss[r]);
            }
    }
    #pragma unroll
    for (int r = 0; r < 4; ++r) {
        ss[r] += __shfl_xor(ss[r], 1);
        ss[r] += __shfl_xor(ss[r], 2);
        ss[r] += __shfl_xor(ss[r], 4);
        ss[r] += __shfl_xor(ss[r], 8);
    }
    float scl[4];
    #pragma unroll
    for (int r = 0; r < 4; ++r) scl[r] = 1.f / fmaxf(sqrtf(ss[r]), 1e-12f);

    if constexpr (!CONV2) {
        // normalize + relu -> rbh (bf16) + BN partial stats (exact f32)
        float sb[8], s2b[8];
        #pragma unroll
        for (int j = 0; j < 8; ++j) { sb[j] = 0.f; s2b[j] = 0.f; }
        int nodeb = nb + w * 16 + kg * 4;
        #pragma unroll
        for (int j = 0; j < 8; ++j)
            #pragma unroll
            for (int r = 0; r < 4; ++r) {
                float h = fmaxf(acc[j][r] * scl[r], 0.f);
                sb[j] += h; s2b[j] = fmaf(h, h, s2b[j]);
                rbh[(size_t)(nodeb + r) * F + j * 16 + li] = f2b(h);
            }
        #pragma unroll
        for (int j = 0; j < 8; ++j) {
            sb[j]  += __shfl_xor(sb[j], 16);  sb[j]  += __shfl_xor(sb[j], 32);
            s2b[j] += __shfl_xor(s2b[j], 16); s2b[j] += __shfl_xor(s2b[j], 32);
        }
        if (kg == 0) {
            #pragma unroll
            for (int j = 0; j < 8; ++j) {
                atomicAdd(&stats[j * 16 + li], sb[j]);
                atomicAdd(&stats[F + j * 16 + li], s2b[j]);
            }
        }
    } else {
        // normalize -> sC (aliases dead weight LDS) -> fused fc
        __syncthreads();        // all waves done reading weights
        float (*sC)[132] = (float(*)[132])smem;
        int row16 = w * 16 + kg * 4;
        #pragma unroll
        for (int j = 0; j < 8; ++j)
            #pragma unroll
            for (int r = 0; r < 4; ++r)
                sC[row16 + r][j * 16 + li] = acc[j][r] * scl[r];
        __syncthreads();
        #pragma unroll
        for (int pp = 0; pp < 4; ++pp) {
            int p = t + pp * 256;
            int n = p >> 4, c = p & 15;
            float s = bfc[c];
            for (int o = 0; o < F; o += 4) {
                float4 h4 = *(const float4*)&sC[n][o];
                float4 w4 = *(const float4*)&Wfc[c * F + o];
                s += h4.x * w4.x + h4.y * w4.y + h4.z * w4.z + h4.w * w4.w;
            }
            out[(size_t)(nb + n) * NC + c] = s;
        }
    }
}

extern "C" void kernel_launch(void* const* d_in, const int* in_sizes, int n_in,
                              void* d_out, int out_size, void* d_ws, size_t ws_size,
                              hipStream_t stream) {
    const float* x     = (const float*)d_in[0];
    const int*   ei    = (const int*)d_in[1];
    const float* W1l   = (const float*)d_in[2];
    const float* b1l   = (const float*)d_in[3];
    const float* W1r   = (const float*)d_in[4];
    const float* gamma = (const float*)d_in[5];
    const float* beta  = (const float*)d_in[6];
    const float* W2l   = (const float*)d_in[7];
    const float* b2l   = (const float*)d_in[8];
    const float* W2r   = (const float*)d_in[9];
    const float* Wfc   = (const float*)d_in[10];
    const float* bfc   = (const float*)d_in[11];

    char* ws = (char*)d_ws;
    int*            rowptr = (int*)(ws + OFF_ROWPTR);
    int*            fill   = (int*)(ws + OFF_FILL);
    int*            bsum   = (int*)(ws + OFF_BSUM);
    int*            sorted = (int*)(ws + OFF_SORTED);
    float*          stats  = (float*)(ws + OFF_STATS);
    float*          bias2  = (float*)(ws + OFF_BIAS2);
    unsigned short* w1lb   = (unsigned short*)(ws + OFF_W1LB);
    unsigned short* w1rb   = (unsigned short*)(ws + OFF_W1RB);
    unsigned short* w2lb   = (unsigned short*)(ws + OFF_W2LB);
    unsigned short* w2rb   = (unsigned short*)(ws + OFF_W2RB);
    unsigned short* rbh    = (unsigned short*)(ws + OFF_RBH);
    unsigned short* aggm   = (unsigned short*)(ws + OFF_AGGM);
    float*          out    = (float*)d_out;

    hipMemsetAsync(fill, 0, NN * sizeof(int), stream);
    hipMemsetAsync(stats, 0, 256 * sizeof(float), stream);

    k_wprep1<<<128, 256, 0, stream>>>(W1l, W1r, w1lb, w1rb);
    k_hist<<<(NE + 255) / 256, 256, 0, stream>>>(ei, fill);
    k_scan1<<<40, 1024, 0, stream>>>(fill, rowptr, bsum);
    k_scan2<<<1, 64, 0, stream>>>(bsum, rowptr);
    k_scan3<<<40, 1024, 0, stream>>>(rowptr, bsum, fill);
    k_scatter<<<(NE + 255) / 256, 256, 0, stream>>>(ei, fill, sorted);

    // conv1
    k_agg<0><<<NN / 4, 256, 0, stream>>>(x, nullptr, rowptr, sorted, aggm);
    k_gemm<0><<<NN / 64, 256, 0, stream>>>(aggm, x, nullptr, w1lb, b1l, nullptr,
                                           rowptr, rbh, stats, nullptr, nullptr, nullptr);
    k_bnfinal<<<1, 128, 0, stream>>>(stats, gamma, beta);
    k_wprep2<<<1, 256, 0, stream>>>(W2l, W2r, b2l, stats, w2lb, w2rb, bias2);

    // conv2 (+ fused fc)
    k_agg<1><<<NN / 4, 256, 0, stream>>>(nullptr, rbh, rowptr, sorted, aggm);
    k_gemm<1><<<NN / 64, 256, 0, stream>>>(aggm, nullptr, rbh, w2lb, nullptr, bias2,
                                           rowptr, nullptr, nullptr, Wfc, bfc, out);
}

// Round 8
// 273.916 us; speedup vs baseline: 1.1931x; 1.1931x over previous
//
#include <hip/hip_runtime.h>

#define NN 40000
#define NE 640000
#define F 128
#define NC 16

typedef __attribute__((ext_vector_type(8))) short bf16x8;   // 8 bf16 (4 VGPRs)
typedef __attribute__((ext_vector_type(4))) float f32x4;    // MFMA acc

// ws layout (bytes); total 23502336 < proven 23632384
#define OFF_ROWPTR 0u          // (NN+1) ints
#define OFF_FILL   163968u     // NN ints
#define OFF_BSUM   327936u     // 64 ints
#define OFF_SORTED 328192u     // NE ints -> 2888192
#define OFF_STATS  2888192u    // 512 f32: sum, sumsq, bn_a, bn_b (2048 B — do not shrink!)
#define OFF_BIAS2  2890240u    // 256 f32: bias2a[128], biasExtra[128]
#define OFF_W1LB   2891264u    // 128x128 bf16
#define OFF_W1RB   2924032u
#define OFF_W2LB   2956800u    // BN-scale-folded
#define OFF_W2RB   2989568u
#define OFF_RBH    3022336u    // NN*F bf16: xb (bf16 of x) then overwritten by h1 (block-exclusive rows)
#define OFF_AGGM   13262336u   // NN*F bf16 -> 23502336

__device__ __forceinline__ unsigned short f2b(float f) {   // f32 -> bf16 RNE
    unsigned u = __builtin_bit_cast(unsigned, f);
    return (unsigned short)((u + 0x7fffu + ((u >> 16) & 1u)) >> 16);
}
__device__ __forceinline__ float b2f(unsigned short s) {
    return __builtin_bit_cast(float, (unsigned)s << 16);
}
__device__ __forceinline__ unsigned pk2(float lo, float hi) {
    return (unsigned)f2b(lo) | ((unsigned)f2b(hi) << 16);
}

__global__ __launch_bounds__(256) void k_hist(const int* __restrict__ ei, int* __restrict__ cnt) {
    int e = blockIdx.x * 256 + threadIdx.x;
    if (e < NE) atomicAdd(&cnt[ei[NE + e]], 1);
}

__global__ __launch_bounds__(1024) void k_scan1(const int* __restrict__ cnt, int* __restrict__ rowptr,
                                                int* __restrict__ bsum) {
    __shared__ int wsum[16];
    int t = threadIdx.x, b = blockIdx.x;
    int idx = b * 1024 + t;
    int v = (idx < NN) ? cnt[idx] : 0;
    int lane = t & 63, w = t >> 6;
    int val = v;
    #pragma unroll
    for (int off = 1; off < 64; off <<= 1) { int u = __shfl_up(val, off); if (lane >= off) val += u; }
    if (lane == 63) wsum[w] = val;
    __syncthreads();
    if (w == 0) {
        int x = (lane < 16) ? wsum[lane] : 0;
        #pragma unroll
        for (int off = 1; off < 16; off <<= 1) { int u = __shfl_up(x, off); if (lane >= off) x += u; }
        if (lane < 16) wsum[lane] = x;
    }
    __syncthreads();
    int excl = val - v + (w > 0 ? wsum[w - 1] : 0);
    if (idx < NN) rowptr[idx] = excl;
    if (t == 1023) bsum[b] = wsum[15];
}

__global__ __launch_bounds__(64) void k_scan2(int* __restrict__ bsum, int* __restrict__ rowptr) {
    int lane = threadIdx.x;
    int v = (lane < 40) ? bsum[lane] : 0;
    int val = v;
    #pragma unroll
    for (int off = 1; off < 64; off <<= 1) { int u = __shfl_up(val, off); if (lane >= off) val += u; }
    if (lane < 40) bsum[lane] = val - v;
    if (lane == 0) rowptr[NN] = NE;
}

__global__ __launch_bounds__(1024) void k_scan3(int* __restrict__ rowptr, const int* __restrict__ bsum,
                                                int* __restrict__ fill) {
    int t = threadIdx.x, b = blockIdx.x;
    int idx = b * 1024 + t;
    if (idx < NN) {
        int r = rowptr[idx] + bsum[b];
        rowptr[idx] = r;
        fill[idx] = r;
    }
}

__global__ __launch_bounds__(256) void k_scatter(const int* __restrict__ ei, int* __restrict__ fill,
                                                 int* __restrict__ sorted) {
    int e = blockIdx.x * 256 + threadIdx.x;
    if (e < NE) {
        int src = ei[e], dst = ei[NE + e];
        int pos = atomicAdd(&fill[dst], 1);
        sorted[pos] = src;
    }
}

__global__ __launch_bounds__(256) void k_wprep1(const float* __restrict__ W1l, const float* __restrict__ W1r,
                                                unsigned short* __restrict__ w1lb, unsigned short* __restrict__ w1rb) {
    int i = blockIdx.x * 256 + threadIdx.x;     // < 32768
    if (i < 16384) w1lb[i] = f2b(W1l[i]);
    else           w1rb[i - 16384] = f2b(W1r[i - 16384]);
}

// x (f32) -> xb (bf16), 8 elems/thread, coalesced
__global__ __launch_bounds__(256) void k_x2b(const float* __restrict__ x, unsigned short* __restrict__ xb) {
    int i = (blockIdx.x * 256 + threadIdx.x) * 8;   // grid covers NN*F
    float4 lo = *(const float4*)&x[i];
    float4 hi = *(const float4*)&x[i + 4];
    uint4 o;
    o.x = pk2(lo.x, lo.y); o.y = pk2(lo.z, lo.w);
    o.z = pk2(hi.x, hi.y); o.w = pk2(hi.z, hi.w);
    *(uint4*)&xb[i] = o;
}

__global__ __launch_bounds__(128) void k_bnfinal(float* __restrict__ stats, const float* __restrict__ gamma,
                                                 const float* __restrict__ beta) {
    int t = threadIdx.x;
    float mu  = stats[t] * (1.f / NN);
    float var = stats[F + t] * (1.f / NN) - mu * mu;
    float a = gamma[t] * rsqrtf(var + 1e-5f);
    stats[256 + t] = a;
    stats[384 + t] = beta[t] - mu * a;
}

// Fold BN affine into conv2 weights + bias vectors.
__global__ __launch_bounds__(256) void k_wprep2(const float* __restrict__ W2l, const float* __restrict__ W2r,
                                                const float* __restrict__ b2l, const float* __restrict__ stats,
                                                unsigned short* __restrict__ w2lb, unsigned short* __restrict__ w2rb,
                                                float* __restrict__ bias2) {
    int t = threadIdx.x;
    int o = t & 127;
    const float* W = (t < 128) ? W2l : W2r;
    unsigned short* wb = (t < 128) ? w2lb : w2rb;
    float dot = 0.f;
    for (int k = 0; k < F; ++k) {
        float w = W[o * F + k];
        wb[o * F + k] = f2b(w * stats[256 + k]);
        dot = fmaf(stats[384 + k], w, dot);
    }
    if (t < 128) bias2[128 + o] = dot;
    else         bias2[o] = b2l[o] + dot;
}

// Gather (neighbor mean), bf16 rows only: one wave per node; quarter q takes edge e+q,
// lane li covers 8 features (16 B loads). No LDS -> full occupancy.
__global__ __launch_bounds__(256) void k_agg(
    const unsigned short* __restrict__ featb,
    const int* __restrict__ rowptr, const int* __restrict__ sorted,
    unsigned short* __restrict__ aggm)
{
    int node = (blockIdx.x << 2) + (threadIdx.x >> 6);
    int lane = threadIdx.x & 63;
    int q = lane >> 4, li = lane & 15;
    int fo = li << 3;
    int e0 = rowptr[node], e1 = rowptr[node + 1];
    int deg = e1 - e0;
    float a0=0.f,a1=0.f,a2=0.f,a3=0.f,a4=0.f,a5=0.f,a6=0.f,a7=0.f;

#define ACC_EDGE(SRC) do { \
        uint4 u = *(const uint4*)&featb[(size_t)(SRC) * F + fo]; \
        a0 += b2f((unsigned short)(u.x & 0xffff)); a1 += b2f((unsigned short)(u.x >> 16)); \
        a2 += b2f((unsigned short)(u.y & 0xffff)); a3 += b2f((unsigned short)(u.y >> 16)); \
        a4 += b2f((unsigned short)(u.z & 0xffff)); a5 += b2f((unsigned short)(u.z >> 16)); \
        a6 += b2f((unsigned short)(u.w & 0xffff)); a7 += b2f((unsigned short)(u.w >> 16)); \
    } while (0)

    int e = e0;
    for (; e + 8 <= e1; e += 8) {
        int s0 = sorted[e + q];
        int s1 = sorted[e + 4 + q];
        ACC_EDGE(s0); ACC_EDGE(s1);
    }
    for (; e + 4 <= e1; e += 4) {
        int s0 = sorted[e + q];
        ACC_EDGE(s0);
    }
    if (e < e1 && q < (e1 - e)) {
        int s0 = sorted[e + q];
        ACC_EDGE(s0);
    }
#undef ACC_EDGE

    #pragma unroll
    for (int m = 16; m <= 32; m <<= 1) {
        a0 += __shfl_xor(a0, m); a1 += __shfl_xor(a1, m);
        a2 += __shfl_xor(a2, m); a3 += __shfl_xor(a3, m);
        a4 += __shfl_xor(a4, m); a5 += __shfl_xor(a5, m);
        a6 += __shfl_xor(a6, m); a7 += __shfl_xor(a7, m);
    }

    if (q == 0) {
        float inv = 1.f / (float)(deg > 1 ? deg : 1);
        uint4 o;
        o.x = pk2(a0 * inv, a1 * inv);
        o.y = pk2(a2 * inv, a3 * inv);
        o.z = pk2(a4 * inv, a5 * inv);
        o.w = pk2(a6 * inv, a7 * inv);
        *(uint4*)&aggm[(size_t)node * F + fo] = o;
    }
}

// MFMA dual GEMM, 64 nodes/block, 4 waves.
// A-tiles (agg 16KB + self 16KB) staged into LDS via COALESCED linear loads (r6/r7 bug:
// per-fragment global loads were 64-lane scattered 16B reads -> 139 GB/s latency death).
// XOR swizzle (addr ^= ((row&7)<<4)) on LDS write+read, r7-verified. Wave w = 32-col slice,
// covers all 64 rows (B-frags from L2-hot global, reused 4x). Epilogue via sC aliasing LDS.
template<int CONV2>
__global__ __launch_bounds__(256) void k_gemm(
    const unsigned short* __restrict__ aggm,
    const unsigned short* __restrict__ selfb,   // conv1: xb, conv2: rbh
    const unsigned short* __restrict__ wlb, const unsigned short* __restrict__ wrb,
    const float* __restrict__ bias1,            // conv1: b1l
    const float* __restrict__ bias2,            // conv2: [bias2a | biasExtra]
    const int* __restrict__ rowptr,
    unsigned short* __restrict__ rbh, float* __restrict__ stats,
    const float* __restrict__ Wfc, const float* __restrict__ bfc,
    float* __restrict__ out)
{
    __shared__ __align__(16) char smem[34048];   // stage 32KB; sC [64][132] f32 = 33792B aliases
    int t = threadIdx.x;
    int nb = blockIdx.x * 64;
    int cp = t >> 6, lane = t & 63;
    int li = lane & 15, kg = lane >> 4;

    // ---- coalesced stage: sAgg [0,16K), sSelf [16K,32K) ----
    const char* srcA = (const char*)(aggm + (size_t)nb * F);
    const char* srcS = (const char*)(selfb + (size_t)nb * F);
    #pragma unroll
    for (int it = 0; it < 8; ++it) {
        unsigned local = (unsigned)(it & 3) * 4096u + (unsigned)t * 16u;
        uint4 v = *(const uint4*)(((it < 4) ? srcA : srcS) + local);
        unsigned d = ((it < 4) ? 0u : 16384u) + local;
        unsigned s = d ^ (((d >> 8) & 7u) << 4);
        *(uint4*)(smem + s) = v;
    }
    __syncthreads();

    // ---- MFMA: wave = cols [cp*32, cp*32+32), rows 0..63 ----
    f32x4 acc[4][2];
    #pragma unroll
    for (int rg = 0; rg < 4; ++rg)
        #pragma unroll
        for (int j = 0; j < 2; ++j) acc[rg][j] = (f32x4){0.f, 0.f, 0.f, 0.f};

    #pragma unroll
    for (int path = 0; path < 2; ++path) {
        const unsigned short* wb = path ? wrb : wlb;
        unsigned sbase = path ? 16384u : 0u;
        #pragma unroll
        for (int kc = 0; kc < 4; ++kc) {
            bf16x8 b0 = *(const bf16x8*)(wb + (size_t)(cp * 32 + li) * F + kg * 8 + kc * 32);
            bf16x8 b1 = *(const bf16x8*)(wb + (size_t)(cp * 32 + 16 + li) * F + kg * 8 + kc * 32);
            #pragma unroll
            for (int rg = 0; rg < 4; ++rg) {
                unsigned ad = sbase + (unsigned)(rg * 16 + li) * 256u + (unsigned)(kg * 16 + kc * 64);
                ad ^= ((unsigned)(li & 7) << 4);
                bf16x8 a = *(const bf16x8*)(smem + ad);
                acc[rg][0] = __builtin_amdgcn_mfma_f32_16x16x32_bf16(a, b0, acc[rg][0], 0, 0, 0);
                acc[rg][1] = __builtin_amdgcn_mfma_f32_16x16x32_bf16(a, b1, acc[rg][1], 0, 0, 0);
            }
        }
    }
    __syncthreads();   // all waves done with staged A

    // ---- C -> sC. C/D layout (verified r6/r7): lane(li,kg) reg r -> row kg*4+r, col li ----
    float (*sC)[132] = (float(*)[132])smem;
    #pragma unroll
    for (int rg = 0; rg < 4; ++rg)
        #pragma unroll
        for (int j = 0; j < 2; ++j)
            #pragma unroll
            for (int r = 0; r < 4; ++r)
                sC[rg * 16 + kg * 4 + r][cp * 32 + j * 16 + li] = acc[rg][j][r];
    __syncthreads();

    // ---- bias + row L2 norm: 4 threads/row, 32 cols each; quad shuffle-reduce ----
    int row = t >> 2, c0 = (t & 3) * 32;
    int node = nb + row;
    float v[32];
    float ss = 0.f;
    if constexpr (!CONV2) {
        #pragma unroll
        for (int cc = 0; cc < 32; ++cc) {
            v[cc] = sC[row][c0 + cc] + bias1[c0 + cc];
            ss = fmaf(v[cc], v[cc], ss);
        }
    } else {
        float flag = (rowptr[node + 1] > rowptr[node]) ? 1.f : 0.f;
        #pragma unroll
        for (int cc = 0; cc < 32; ++cc) {
            v[cc] = sC[row][c0 + cc] + bias2[c0 + cc] + flag * bias2[128 + c0 + cc];
            ss = fmaf(v[cc], v[cc], ss);
        }
    }
    ss += __shfl_xor(ss, 1);
    ss += __shfl_xor(ss, 2);
    float scl = 1.f / fmaxf(sqrtf(ss), 1e-12f);

    if constexpr (!CONV2) {
        // normalize + relu -> sC (f32, for BN stats) + rbh (bf16, coalesced uint4)
        uint4 p0, p1;
        #pragma unroll
        for (int cc = 0; cc < 32; ++cc) {
            v[cc] = fmaxf(v[cc] * scl, 0.f);
            sC[row][c0 + cc] = v[cc];
        }
        p0.x = pk2(v[0], v[1]);   p0.y = pk2(v[2], v[3]);
        p0.z = pk2(v[4], v[5]);   p0.w = pk2(v[6], v[7]);
        p1.x = pk2(v[8], v[9]);   p1.y = pk2(v[10], v[11]);
        p1.z = pk2(v[12], v[13]); p1.w = pk2(v[14], v[15]);
        *(uint4*)&rbh[(size_t)node * F + c0]     = p0;
        *(uint4*)&rbh[(size_t)node * F + c0 + 8] = p1;
        p0.x = pk2(v[16], v[17]); p0.y = pk2(v[18], v[19]);
        p0.z = pk2(v[20], v[21]); p0.w = pk2(v[22], v[23]);
        p1.x = pk2(v[24], v[25]); p1.y = pk2(v[26], v[27]);
        p1.z = pk2(v[28], v[29]); p1.w = pk2(v[30], v[31]);
        *(uint4*)&rbh[(size_t)node * F + c0 + 16] = p0;
        *(uint4*)&rbh[(size_t)node * F + c0 + 24] = p1;
        __syncthreads();
        if (t < F) {    // column stats over 64 rows (conflict-free: consecutive t -> consecutive banks)
            float s = 0.f, s2 = 0.f;
            #pragma unroll 8
            for (int r = 0; r < 64; ++r) {
                float h = sC[r][t];
                s += h; s2 = fmaf(h, h, s2);
            }
            atomicAdd(&stats[t], s);
            atomicAdd(&stats[F + t], s2);
        }
    } else {
        #pragma unroll
        for (int cc = 0; cc < 32; ++cc) sC[row][c0 + cc] = v[cc] * scl;
        __syncthreads();
        // fused fc: 64 nodes x 16 classes = 1024 dots
        #pragma unroll
        for (int pp = 0; pp < 4; ++pp) {
            int p = t + pp * 256;
            int n = p >> 4, c = p & 15;
            float s = bfc[c];
            for (int o = 0; o < F; o += 4) {
                float4 h4 = *(const float4*)&sC[n][o];
                float4 w4 = *(const float4*)&Wfc[c * F + o];
                s += h4.x * w4.x + h4.y * w4.y + h4.z * w4.z + h4.w * w4.w;
            }
            out[(size_t)(nb + n) * NC + c] = s;
        }
    }
}

extern "C" void kernel_launch(void* const* d_in, const int* in_sizes, int n_in,
                              void* d_out, int out_size, void* d_ws, size_t ws_size,
                              hipStream_t stream) {
    const float* x     = (const float*)d_in[0];
    const int*   ei    = (const int*)d_in[1];
    const float* W1l   = (const float*)d_in[2];
    const float* b1l   = (const float*)d_in[3];
    const float* W1r   = (const float*)d_in[4];
    const float* gamma = (const float*)d_in[5];
    const float* beta  = (const float*)d_in[6];
    const float* W2l   = (const float*)d_in[7];
    const float* b2l   = (const float*)d_in[8];
    const float* W2r   = (const float*)d_in[9];
    const float* Wfc   = (const float*)d_in[10];
    const float* bfc   = (const float*)d_in[11];

    char* ws = (char*)d_ws;
    int*            rowptr = (int*)(ws + OFF_ROWPTR);
    int*            fill   = (int*)(ws + OFF_FILL);
    int*            bsum   = (int*)(ws + OFF_BSUM);
    int*            sorted = (int*)(ws + OFF_SORTED);
    float*          stats  = (float*)(ws + OFF_STATS);
    float*          bias2  = (float*)(ws + OFF_BIAS2);
    unsigned short* w1lb   = (unsigned short*)(ws + OFF_W1LB);
    unsigned short* w1rb   = (unsigned short*)(ws + OFF_W1RB);
    unsigned short* w2lb   = (unsigned short*)(ws + OFF_W2LB);
    unsigned short* w2rb   = (unsigned short*)(ws + OFF_W2RB);
    unsigned short* rbh    = (unsigned short*)(ws + OFF_RBH);   // xb then h1
    unsigned short* aggm   = (unsigned short*)(ws + OFF_AGGM);
    float*          out    = (float*)d_out;

    hipMemsetAsync(fill, 0, NN * sizeof(int), stream);
    hipMemsetAsync(stats, 0, 256 * sizeof(float), stream);

    k_wprep1<<<128, 256, 0, stream>>>(W1l, W1r, w1lb, w1rb);
    k_x2b<<<NN * F / (256 * 8), 256, 0, stream>>>(x, rbh);
    k_hist<<<(NE + 255) / 256, 256, 0, stream>>>(ei, fill);
    k_scan1<<<40, 1024, 0, stream>>>(fill, rowptr, bsum);
    k_scan2<<<1, 64, 0, stream>>>(bsum, rowptr);
    k_scan3<<<40, 1024, 0, stream>>>(rowptr, bsum, fill);
    k_scatter<<<(NE + 255) / 256, 256, 0, stream>>>(ei, fill, sorted);

    // conv1: gather(xb) -> gemm (reads xb rows, writes h1 over same rows)
    k_agg<<<NN / 4, 256, 0, stream>>>(rbh, rowptr, sorted, aggm);
    k_gemm<0><<<NN / 64, 256, 0, stream>>>(aggm, rbh, w1lb, w1rb, b1l, nullptr,
                                           rowptr, rbh, stats, nullptr, nullptr, nullptr);
    k_bnfinal<<<1, 128, 0, stream>>>(stats, gamma, beta);
    k_wprep2<<<1, 256, 0, stream>>>(W2l, W2r, b2l, stats, w2lb, w2rb, bias2);

    // conv2 (+ fused fc)
    k_agg<<<NN / 4, 256, 0, stream>>>(rbh, rowptr, sorted, aggm);
    k_gemm<1><<<NN / 64, 256, 0, stream>>>(aggm, rbh, w2lb, w2rb, nullptr, bias2,
                                           rowptr, nullptr, nullptr, Wfc, bfc, out);
}